// Round 9
// baseline (196.723 us; speedup 1.0000x reference)
//
#include <hip/hip_runtime.h>
#include <cstddef>

#define B_   16
#define C_   256
#define HW_  4096

typedef __attribute__((ext_vector_type(8)))  short bf16x8;
typedef __attribute__((ext_vector_type(16))) float f32x16;

static __device__ __forceinline__ unsigned short f2bf(float f) {
    unsigned int u = __float_as_uint(f);
    u += 0x7fffu + ((u >> 16) & 1u);          // RNE
    return (unsigned short)(u >> 16);
}

// ---------------------------------------------------------------------------
// Kernel E v2: fused square + NCHW->NHWC bf16 + per-(b,q,h) energy argmax
// partials. grid = (b,h) = 1024 blocks x 256 thr. (verified R5)
// ---------------------------------------------------------------------------
__global__ __launch_bounds__(256) void fused_energy(const float* __restrict__ x,
                                                    unsigned short* __restrict__ xsqN,
                                                    float* __restrict__ pval,
                                                    int* __restrict__ pidx) {
    int blk = blockIdx.x;
    int b = blk >> 6, h = blk & 63;
    int tid = threadIdx.x;
    int tl  = tid >> 4;           // 0..15 channel-lane group
    int w4  = (tid & 15) << 2;    // w base 0,4,...,60
    int wv  = tid >> 6;           // wave 0..3
    __shared__ float earr[4][4][64];            // [wave][q][w]
    __shared__ unsigned short tile[64][264];    // row stride 264 ush = 528B
    const float* xb = x + (size_t)b * C_ * HW_ + h * 64 + w4;

    float e[4][4];                // [quadrant][ww]
#pragma unroll
    for (int q = 0; q < 4; ++q)
#pragma unroll
        for (int ww = 0; ww < 4; ++ww) e[q][ww] = 0.f;

#pragma unroll
    for (int i = 0; i < 4; ++i) {             // quadrant = i (compile-time)
        int c4 = tl * 4 + 64 * i;             // 4 consecutive channels
        float sq[4][4];                       // [k=channel][ww]
#pragma unroll
        for (int k = 0; k < 4; ++k) {
            float4 v = *(const float4*)(xb + (size_t)(c4 + k) * HW_);
            sq[k][0] = v.x * v.x; sq[k][1] = v.y * v.y;
            sq[k][2] = v.z * v.z; sq[k][3] = v.w * v.w;
            e[i][0] += sq[k][0]; e[i][1] += sq[k][1];
            e[i][2] += sq[k][2]; e[i][3] += sq[k][3];
        }
#pragma unroll
        for (int ww = 0; ww < 4; ++ww) {      // pack 4 channels -> ushort4
            uint2 p;
            p.x = (unsigned)f2bf(sq[0][ww]) | ((unsigned)f2bf(sq[1][ww]) << 16);
            p.y = (unsigned)f2bf(sq[2][ww]) | ((unsigned)f2bf(sq[3][ww]) << 16);
            *(uint2*)(&tile[w4 + ww][c4]) = p;
        }
    }

    // wave-local reduce over the 4 tl-groups within this wave (tid bits 4,5)
#pragma unroll
    for (int q = 0; q < 4; ++q)
#pragma unroll
        for (int ww = 0; ww < 4; ++ww) {
            float v = e[q][ww];
            v += __shfl_xor(v, 16);
            v += __shfl_xor(v, 32);
            e[q][ww] = v;
        }
    if ((tid & 48) == 0) {
#pragma unroll
        for (int q = 0; q < 4; ++q) {
            float4 v; v.x = e[q][0]; v.y = e[q][1]; v.z = e[q][2]; v.w = e[q][3];
            *(float4*)&earr[wv][q][w4] = v;
        }
    }
    __syncthreads();

    // contiguous NHWC stores: 32 lanes cover one 512B row segment
    size_t base = (size_t)(b * 64 + h) * 64 * 256;
#pragma unroll
    for (int it = 0; it < 8; ++it) {
        int row  = it * 8 + (tid >> 5);
        int col8 = (tid & 31) * 8;
        *(int4*)(xsqN + base + (size_t)row * 256 + col8) = *(int4*)&tile[row][col8];
    }

    int q = tid >> 6;
    int w = tid & 63;
    float ev = earr[0][q][w] + earr[1][q][w] + earr[2][q][w] + earr[3][q][w];
    int ix = h * 64 + w;
#pragma unroll
    for (int off = 32; off; off >>= 1) {
        float ov = __shfl_down(ev, off);
        int   oi = __shfl_down(ix, off);
        if (ov > ev || (ov == ev && oi < ix)) { ev = ov; ix = oi; }
    }
    if ((tid & 63) == 0) {
        pval[(b * 64 + h) * 4 + q] = ev;
        pidx[(b * 64 + h) * 4 + q] = ix;
    }
}

// ---------------------------------------------------------------------------
// Final argmax over h per (b,q) FUSED with landmark value gather.
// grid = 64 blocks (b*4+q) x 64 thr. (verified R5)
// ---------------------------------------------------------------------------
__global__ __launch_bounds__(64) void energy_final(const float* __restrict__ pval,
                                                   const int* __restrict__ pidx,
                                                   int* __restrict__ lm,
                                                   const unsigned short* __restrict__ xsqN,
                                                   unsigned short* __restrict__ Lval) {
    int bq = blockIdx.x;
    int b = bq >> 2, q = bq & 3;
    int t = threadIdx.x;
    float ev = pval[(b * 64 + t) * 4 + q];
    int   ix = pidx[(b * 64 + t) * 4 + q];
#pragma unroll
    for (int off = 32; off; off >>= 1) {
        float ov = __shfl_down(ev, off);
        int   oi = __shfl_down(ix, off);
        if (ov > ev || (ov == ev && oi < ix)) { ev = ov; ix = oi; }
    }
    int ix0 = __shfl(ix, 0);
    if (t == 0) lm[bq] = ix0;
    Lval[b * 256 + q * 64 + t] =
        xsqN[((size_t)((b * 64 + (ix0 >> 6)) * 64 + (ix0 & 63))) * 256 + q * 64 + t];
}

// ---------------------------------------------------------------------------
// Weight pack v3 -> fragment-ordered bf16, CIB-MAJOR chunk order:
//   chunk c' = cib*9 + j at offset c'*8192 ushorts (16KB). (verified R8)
// grid = 64 blocks (cog*8+cib) x 256 thr.
// ---------------------------------------------------------------------------
__global__ __launch_bounds__(256) void wt_pack(const float* __restrict__ w,
                                               unsigned short* __restrict__ wa) {
    int blk = blockIdx.x;
    int cog = blk >> 3, cib = blk & 7;
    int tid = threadIdx.x;
    __shared__ unsigned short wlds[32][292];   // [co_l][cc*9+j], pad 288->292
    {
        int co_l = tid >> 3;          // 0..31
        int seg  = tid & 7;           // 0..7, 36 consecutive floats each
        const float* src = w + ((size_t)((cog * 32 + co_l) * 256 + cib * 32)) * 9 + seg * 36;
#pragma unroll
        for (int f4 = 0; f4 < 9; ++f4) {
            float4 v = *(const float4*)(src + f4 * 4);
            uint2 p;
            p.x = (unsigned)f2bf(v.x) | ((unsigned)f2bf(v.y) << 16);
            p.y = (unsigned)f2bf(v.z) | ((unsigned)f2bf(v.w) << 16);
            *(uint2*)(&wlds[co_l][seg * 36 + f4 * 4]) = p;
        }
    }
    __syncthreads();
    for (int idx = tid; idx < 1152; idx += 256) {   // 9j x 2s x 64 lanes
        int lane = idx & 63;
        int s    = (idx >> 6) & 1;
        int j    = idx >> 7;          // 0..8
        int co_l = lane & 31;
        int k0   = s * 16 + (lane >> 5) * 8;
        union { unsigned short us[8]; int4 v; } u;
#pragma unroll
        for (int jj = 0; jj < 8; ++jj)
            u.us[jj] = wlds[co_l][(k0 + jj) * 9 + j];
        int ob = (cib * 9 + j) * 16 + s * 8 + cog;   // cib-major chunk order
        *(int4*)(wa + ((size_t)ob * 64 + lane) * 8) = u.v;
    }
}

// ---------------------------------------------------------------------------
// B-tile helpers (512-thread block): register load, then rect-max + LDS store.
// ---------------------------------------------------------------------------
static __device__ __forceinline__ void load_B(int4 sv[4],
                                              const unsigned short* __restrict__ xsqN,
                                              int b, int h0, int nc, int tid) {
#pragma unroll
    for (int t2 = 0; t2 < 4; ++t2) {
        int idx = tid + t2 * 512;
        int4 v = {0, 0, 0, 0};
        if (idx < 1584) {
            int pr = idx / 264; int rem = idx - pr * 264;
            int pc = rem >> 2;  int part = rem & 3;
            int grow = h0 - 1 + pr, gcol = pc - 1;
            if ((unsigned)grow < 64u && (unsigned)gcol < 64u)
                v = *(const int4*)(xsqN + (((size_t)(b * 64 + grow) * 64 + gcol) * 256 + nc * 32 + part * 8));
        }
        sv[t2] = v;
    }
}

static __device__ __forceinline__ void store_B(const int4 sv[4],
                                               unsigned short* __restrict__ Bw,
                                               const unsigned short* __restrict__ Lval,
                                               const int* __restrict__ lm,
                                               int b, int h0, int nc, int tid) {
    int l = lm[b * 4 + (nc >> 1)];
    int hm = l >> 6, wm = l & 63;
    bool qhle = (nc >> 1) < 2;          // quadrants 0,1: h <= hm
    bool qwle = ((nc >> 1) & 1) == 0;   // quadrants 0,2: w <= wm
#pragma unroll
    for (int t2 = 0; t2 < 4; ++t2) {
        int idx = tid + t2 * 512;
        if (idx < 1584) {
            int pr = idx / 264; int rem = idx - pr * 264;
            int pc = rem >> 2;  int part = rem & 3;
            int grow = h0 - 1 + pr, gcol = pc - 1;
            union { int4 v; unsigned short us[8]; } u; u.v = sv[t2];
            bool inb = ((unsigned)grow < 64u) && ((unsigned)gcol < 64u);
            bool hok = qhle ? (grow <= hm) : (grow >= hm);
            bool wok = qwle ? (gcol <= wm) : (gcol >= wm);
            if (inb && hok && wok) {
                union { int4 v; unsigned short us[8]; } Lu;
                Lu.v = *(const int4*)(Lval + b * 256 + nc * 32 + part * 8);
#pragma unroll
                for (int k = 0; k < 8; ++k)
                    if (Lu.us[k] > u.us[k]) u.us[k] = Lu.us[k];  // bf16 >=0: bit-compare valid
            }
            *(int4*)(&Bw[(pr * 66 + pc) * 40 + part * 8]) = u.v;
        }
    }
}

// ---------------------------------------------------------------------------
// Conv v6: 3-tap phases + global_load_lds A staging (R8, verified) PLUS
// half-tap operand software pipeline + setprio.
//   R8 PMC arithmetic: phase = 8300 cy = 3 x (ds_read 1160 + MFMA 1024) +
//   ~1700 overhead -> operand reads and MFMAs fully SERIALIZE (all waves
//   read-then-MFMA in sync; LDS idle during MFMA burst and vice versa).
//   Fix (T3 at register level): double-buffered named operand sets; issue
//   half-tap h+1's 6 b128 reads while half h's 8 MFMAs execute (compiler
//   inserts counted lgkmcnt). setprio(1) around MFMA cluster (T5: pipeline
//   creates read/MFMA role-split across waves).
// LDS: As 2x48KB + Bs 2x31.7KB = 161.7 KB, 1 block/CU. Grid 256.
// ---------------------------------------------------------------------------
__global__ __launch_bounds__(512, 2) void conv_mfma(const unsigned short* __restrict__ xsqN,
                                                    const unsigned short* __restrict__ wa,
                                                    const float* __restrict__ bias,
                                                    const int* __restrict__ lm,
                                                    const unsigned short* __restrict__ Lval,
                                                    float* __restrict__ out) {
    int pt = blockIdx.x;              // b*16 + hq
    int b  = pt >> 4;
    int h0 = (pt & 15) * 4;
    int tid  = threadIdx.x;
    int lane = tid & 63;
    int wv   = tid >> 6;
    int wy = wv >> 2, wx = wv & 3;    // co half / image row
    int l31 = lane & 31, qh = lane >> 5;

    __shared__ unsigned short Bs[2][6 * 66 * 40];   // 63.4 KB
    __shared__ unsigned short As[2][3 * 8192];      // 98.3 KB (3 taps/phase)

    f32x16 acc[4][2];
#pragma unroll
    for (int mt = 0; mt < 4; ++mt)
#pragma unroll
        for (int nt = 0; nt < 2; ++nt)
#pragma unroll
            for (int r = 0; r < 16; ++r) acc[mt][nt][r] = 0.f;

    int4 sv[4];   // B prefetch registers (live across one cib)

    // ---- prologue: B(cib=0) into Bs[0]; A phase 0 (chunks 0..2) into As[0]
    load_B(sv, xsqN, b, h0, 0, tid);
    {
        const unsigned short* s0 = wa + wv * 3072 + lane * 8;
#pragma unroll
        for (int k = 0; k < 6; ++k)
            __builtin_amdgcn_global_load_lds(s0 + k * 512, &As[0][wv * 3072 + k * 512], 16, 0, 0);
    }
    store_B(sv, &Bs[0][0], Lval, lm, b, h0, 0, tid);
    __syncthreads();

    for (int cib = 0; cib < 8; ++cib) {
#pragma unroll
        for (int sub = 0; sub < 3; ++sub) {
            int ph = cib * 3 + sub;

            // ---- A DMA stage for next phase (issued first: max MFMA cover)
            if (ph < 23) {
                const unsigned short* s0 = wa + (size_t)(ph + 1) * 24576 + wv * 3072 + lane * 8;
                unsigned short* d0 = &As[(ph + 1) & 1][wv * 3072];
#pragma unroll
                for (int k = 0; k < 6; ++k)
                    __builtin_amdgcn_global_load_lds(s0 + k * 512, d0 + k * 512, 16, 0, 0);
            }
            // ---- B global prefetch for cib+1 (once per cib)
            if (sub == 0 && cib < 7)
                load_B(sv, xsqN, b, h0, cib + 1, tid);

            // ---- MFMA: 3 taps = 6 half-taps, operand double-buffered ----
            const unsigned short* Ab = &As[ph & 1][0];
            const unsigned short* Bb = &Bs[cib & 1][0];

            bf16x8 opA[2][4];   // [buf][m-tile] — all indices compile-time
            bf16x8 opB[2][2];   // [buf][n-tile]

            // preload half 0 (tt=0, s=0)
            {
                const bf16x8* ap = (const bf16x8*)(Ab + (((0 * 8 + wy * 4) * 64 + lane) << 3));
                opA[0][0] = ap[0];
                opA[0][1] = ap[64];
                opA[0][2] = ap[128];
                opA[0][3] = ap[192];
                int j  = sub * 3;
                int r  = wx + j / 3;
                int w0 = l31 + j % 3;
                const unsigned short* Bp = Bb + (r * 66 + w0) * 40 + qh * 8;
                opB[0][0] = *(const bf16x8*)(Bp);
                opB[0][1] = *(const bf16x8*)(Bp + 1280);
            }

#pragma unroll
            for (int hh = 0; hh < 6; ++hh) {
                const int cb = hh & 1;                // current operand buffer
                // ---- prefetch half hh+1 into the other buffer
                if (hh < 5) {
                    const int hn = hh + 1;
                    const int tn = hn >> 1, sn = hn & 1;
                    const unsigned short* At = Ab + tn * 8192;
                    const bf16x8* ap = (const bf16x8*)(At + (((sn * 8 + wy * 4) * 64 + lane) << 3));
                    opA[cb ^ 1][0] = ap[0];
                    opA[cb ^ 1][1] = ap[64];
                    opA[cb ^ 1][2] = ap[128];
                    opA[cb ^ 1][3] = ap[192];
                    int j  = sub * 3 + tn;
                    int r  = wx + j / 3;
                    int w0 = l31 + j % 3;
                    const unsigned short* Bp = Bb + (r * 66 + w0) * 40 + qh * 8 + sn * 16;
                    opB[cb ^ 1][0] = *(const bf16x8*)(Bp);
                    opB[cb ^ 1][1] = *(const bf16x8*)(Bp + 1280);
                }
                // ---- 8 MFMAs with current buffer
                __builtin_amdgcn_s_setprio(1);
                acc[0][0] = __builtin_amdgcn_mfma_f32_32x32x16_bf16(opA[cb][0], opB[cb][0], acc[0][0], 0, 0, 0);
                acc[0][1] = __builtin_amdgcn_mfma_f32_32x32x16_bf16(opA[cb][0], opB[cb][1], acc[0][1], 0, 0, 0);
                acc[1][0] = __builtin_amdgcn_mfma_f32_32x32x16_bf16(opA[cb][1], opB[cb][0], acc[1][0], 0, 0, 0);
                acc[1][1] = __builtin_amdgcn_mfma_f32_32x32x16_bf16(opA[cb][1], opB[cb][1], acc[1][1], 0, 0, 0);
                acc[2][0] = __builtin_amdgcn_mfma_f32_32x32x16_bf16(opA[cb][2], opB[cb][0], acc[2][0], 0, 0, 0);
                acc[2][1] = __builtin_amdgcn_mfma_f32_32x32x16_bf16(opA[cb][2], opB[cb][1], acc[2][1], 0, 0, 0);
                acc[3][0] = __builtin_amdgcn_mfma_f32_32x32x16_bf16(opA[cb][3], opB[cb][0], acc[3][0], 0, 0, 0);
                acc[3][1] = __builtin_amdgcn_mfma_f32_32x32x16_bf16(opA[cb][3], opB[cb][1], acc[3][1], 0, 0, 0);
                __builtin_amdgcn_s_setprio(0);
            }

            // ---- B rect-max + store for cib+1 (into other buffer, last sub)
            if (sub == 2 && cib < 7)
                store_B(sv, &Bs[(cib + 1) & 1][0], Lval, lm, b, h0, cib + 1, tid);

            __syncthreads();
        }
    }

    // ---- epilogue ----
    int h = h0 + wx;
#pragma unroll
    for (int mt = 0; mt < 4; ++mt) {
#pragma unroll
        for (int nt = 0; nt < 2; ++nt) {
#pragma unroll
            for (int r = 0; r < 16; ++r) {
                int row = (r & 3) + 8 * (r >> 2) + 4 * qh;
                int co  = wy * 128 + mt * 32 + row;
                int w   = nt * 32 + l31;
                out[(((size_t)(b * 256 + co)) * 64 + h) * 64 + w] = acc[mt][nt][r] + bias[co];
            }
        }
    }
}

// ---------------------------------------------------------------------------
extern "C" void kernel_launch(void* const* d_in, const int* in_sizes, int n_in,
                              void* d_out, int out_size, void* d_ws, size_t ws_size,
                              hipStream_t stream) {
    const float* x      = (const float*)d_in[0];
    const float* weight = (const float*)d_in[1];
    const float* bias   = (const float*)d_in[2];
    float* out = (float*)d_out;

    char* ws = (char*)d_ws;
    int*            lmp  = (int*)ws;                         // 64 ints @0
    float*          pval = (float*)(ws + 256);               // 4096 f
    int*            pidx = (int*)(ws + 256 + 16384);         // 4096 i
    unsigned short* Lval = (unsigned short*)(ws + 256 + 32768);  // 4096 ush
    unsigned short* Wa   = (unsigned short*)(ws + 49152);    // 1.18 MB
    unsigned short* xsqN = (unsigned short*)(ws + 49152 + 1179648); // NHWC bf16 33.55 MB

    hipLaunchKernelGGL(fused_energy, dim3(1024), dim3(256), 0, stream, x, xsqN, pval, pidx);
    hipLaunchKernelGGL(energy_final, dim3(64), dim3(64), 0, stream, pval, pidx, lmp, xsqN, Lval);
    hipLaunchKernelGGL(wt_pack, dim3(64), dim3(256), 0, stream, weight, Wa);
    hipLaunchKernelGGL(conv_mfma, dim3(256), dim3(512), 0, stream, xsqN, Wa, bias, lmp, Lval, out);
}

// Round 11
// 187.232 us; speedup vs baseline: 1.0507x; 1.0507x over previous
//
#include <hip/hip_runtime.h>
#include <cstddef>

#define B_   16
#define C_   256
#define HW_  4096

typedef __attribute__((ext_vector_type(8)))  short bf16x8;
typedef __attribute__((ext_vector_type(16))) float f32x16;

static __device__ __forceinline__ unsigned short f2bf(float f) {
    unsigned int u = __float_as_uint(f);
    u += 0x7fffu + ((u >> 16) & 1u);          // RNE
    return (unsigned short)(u >> 16);
}

// ---------------------------------------------------------------------------
// Kernel E v2: fused square + NCHW->NHWC bf16 + per-(b,q,h) energy argmax
// partials. grid = (b,h) = 1024 blocks x 256 thr. (verified R5)
// ---------------------------------------------------------------------------
__global__ __launch_bounds__(256) void fused_energy(const float* __restrict__ x,
                                                    unsigned short* __restrict__ xsqN,
                                                    float* __restrict__ pval,
                                                    int* __restrict__ pidx) {
    int blk = blockIdx.x;
    int b = blk >> 6, h = blk & 63;
    int tid = threadIdx.x;
    int tl  = tid >> 4;           // 0..15 channel-lane group
    int w4  = (tid & 15) << 2;    // w base 0,4,...,60
    int wv  = tid >> 6;           // wave 0..3
    __shared__ float earr[4][4][64];            // [wave][q][w]
    __shared__ unsigned short tile[64][264];    // row stride 264 ush = 528B
    const float* xb = x + (size_t)b * C_ * HW_ + h * 64 + w4;

    float e[4][4];                // [quadrant][ww]
#pragma unroll
    for (int q = 0; q < 4; ++q)
#pragma unroll
        for (int ww = 0; ww < 4; ++ww) e[q][ww] = 0.f;

#pragma unroll
    for (int i = 0; i < 4; ++i) {             // quadrant = i (compile-time)
        int c4 = tl * 4 + 64 * i;             // 4 consecutive channels
        float sq[4][4];                       // [k=channel][ww]
#pragma unroll
        for (int k = 0; k < 4; ++k) {
            float4 v = *(const float4*)(xb + (size_t)(c4 + k) * HW_);
            sq[k][0] = v.x * v.x; sq[k][1] = v.y * v.y;
            sq[k][2] = v.z * v.z; sq[k][3] = v.w * v.w;
            e[i][0] += sq[k][0]; e[i][1] += sq[k][1];
            e[i][2] += sq[k][2]; e[i][3] += sq[k][3];
        }
#pragma unroll
        for (int ww = 0; ww < 4; ++ww) {      // pack 4 channels -> ushort4
            uint2 p;
            p.x = (unsigned)f2bf(sq[0][ww]) | ((unsigned)f2bf(sq[1][ww]) << 16);
            p.y = (unsigned)f2bf(sq[2][ww]) | ((unsigned)f2bf(sq[3][ww]) << 16);
            *(uint2*)(&tile[w4 + ww][c4]) = p;
        }
    }

    // wave-local reduce over the 4 tl-groups within this wave (tid bits 4,5)
#pragma unroll
    for (int q = 0; q < 4; ++q)
#pragma unroll
        for (int ww = 0; ww < 4; ++ww) {
            float v = e[q][ww];
            v += __shfl_xor(v, 16);
            v += __shfl_xor(v, 32);
            e[q][ww] = v;
        }
    if ((tid & 48) == 0) {
#pragma unroll
        for (int q = 0; q < 4; ++q) {
            float4 v; v.x = e[q][0]; v.y = e[q][1]; v.z = e[q][2]; v.w = e[q][3];
            *(float4*)&earr[wv][q][w4] = v;
        }
    }
    __syncthreads();

    // contiguous NHWC stores: 32 lanes cover one 512B row segment
    size_t base = (size_t)(b * 64 + h) * 64 * 256;
#pragma unroll
    for (int it = 0; it < 8; ++it) {
        int row  = it * 8 + (tid >> 5);
        int col8 = (tid & 31) * 8;
        *(int4*)(xsqN + base + (size_t)row * 256 + col8) = *(int4*)&tile[row][col8];
    }

    int q = tid >> 6;
    int w = tid & 63;
    float ev = earr[0][q][w] + earr[1][q][w] + earr[2][q][w] + earr[3][q][w];
    int ix = h * 64 + w;
#pragma unroll
    for (int off = 32; off; off >>= 1) {
        float ov = __shfl_down(ev, off);
        int   oi = __shfl_down(ix, off);
        if (ov > ev || (ov == ev && oi < ix)) { ev = ov; ix = oi; }
    }
    if ((tid & 63) == 0) {
        pval[(b * 64 + h) * 4 + q] = ev;
        pidx[(b * 64 + h) * 4 + q] = ix;
    }
}

// ---------------------------------------------------------------------------
// Final argmax over h per (b,q) FUSED with landmark value gather.
// grid = 64 blocks (b*4+q) x 64 thr. (verified R5)
// ---------------------------------------------------------------------------
__global__ __launch_bounds__(64) void energy_final(const float* __restrict__ pval,
                                                   const int* __restrict__ pidx,
                                                   int* __restrict__ lm,
                                                   const unsigned short* __restrict__ xsqN,
                                                   unsigned short* __restrict__ Lval) {
    int bq = blockIdx.x;
    int b = bq >> 2, q = bq & 3;
    int t = threadIdx.x;
    float ev = pval[(b * 64 + t) * 4 + q];
    int   ix = pidx[(b * 64 + t) * 4 + q];
#pragma unroll
    for (int off = 32; off; off >>= 1) {
        float ov = __shfl_down(ev, off);
        int   oi = __shfl_down(ix, off);
        if (ov > ev || (ov == ev && oi < ix)) { ev = ov; ix = oi; }
    }
    int ix0 = __shfl(ix, 0);
    if (t == 0) lm[bq] = ix0;
    Lval[b * 256 + q * 64 + t] =
        xsqN[((size_t)((b * 64 + (ix0 >> 6)) * 64 + (ix0 & 63))) * 256 + q * 64 + t];
}

// ---------------------------------------------------------------------------
// Weight pack v3 -> fragment-ordered bf16, CIB-MAJOR chunk order:
//   chunk c' = cib*9 + j at offset c'*8192 ushorts (16KB). (verified R8)
// grid = 64 blocks (cog*8+cib) x 256 thr.
// ---------------------------------------------------------------------------
__global__ __launch_bounds__(256) void wt_pack(const float* __restrict__ w,
                                               unsigned short* __restrict__ wa) {
    int blk = blockIdx.x;
    int cog = blk >> 3, cib = blk & 7;
    int tid = threadIdx.x;
    __shared__ unsigned short wlds[32][292];   // [co_l][cc*9+j], pad 288->292
    {
        int co_l = tid >> 3;          // 0..31
        int seg  = tid & 7;           // 0..7, 36 consecutive floats each
        const float* src = w + ((size_t)((cog * 32 + co_l) * 256 + cib * 32)) * 9 + seg * 36;
#pragma unroll
        for (int f4 = 0; f4 < 9; ++f4) {
            float4 v = *(const float4*)(src + f4 * 4);
            uint2 p;
            p.x = (unsigned)f2bf(v.x) | ((unsigned)f2bf(v.y) << 16);
            p.y = (unsigned)f2bf(v.z) | ((unsigned)f2bf(v.w) << 16);
            *(uint2*)(&wlds[co_l][seg * 36 + f4 * 4]) = p;
        }
    }
    __syncthreads();
    for (int idx = tid; idx < 1152; idx += 256) {   // 9j x 2s x 64 lanes
        int lane = idx & 63;
        int s    = (idx >> 6) & 1;
        int j    = idx >> 7;          // 0..8
        int co_l = lane & 31;
        int k0   = s * 16 + (lane >> 5) * 8;
        union { unsigned short us[8]; int4 v; } u;
#pragma unroll
        for (int jj = 0; jj < 8; ++jj)
            u.us[jj] = wlds[co_l][(k0 + jj) * 9 + j];
        int ob = (cib * 9 + j) * 16 + s * 8 + cog;   // cib-major chunk order
        *(int4*)(wa + ((size_t)ob * 64 + lane) * 8) = u.v;
    }
}

// ---------------------------------------------------------------------------
// B-tile helpers (512-thread block): register load, then rect-max + LDS store.
// ---------------------------------------------------------------------------
static __device__ __forceinline__ void load_B(int4 sv[4],
                                              const unsigned short* __restrict__ xsqN,
                                              int b, int h0, int nc, int tid) {
#pragma unroll
    for (int t2 = 0; t2 < 4; ++t2) {
        int idx = tid + t2 * 512;
        int4 v = {0, 0, 0, 0};
        if (idx < 1584) {
            int pr = idx / 264; int rem = idx - pr * 264;
            int pc = rem >> 2;  int part = rem & 3;
            int grow = h0 - 1 + pr, gcol = pc - 1;
            if ((unsigned)grow < 64u && (unsigned)gcol < 64u)
                v = *(const int4*)(xsqN + (((size_t)(b * 64 + grow) * 64 + gcol) * 256 + nc * 32 + part * 8));
        }
        sv[t2] = v;
    }
}

static __device__ __forceinline__ void store_B(const int4 sv[4],
                                               unsigned short* __restrict__ Bw,
                                               const unsigned short* __restrict__ Lval,
                                               const int* __restrict__ lm,
                                               int b, int h0, int nc, int tid) {
    int l = lm[b * 4 + (nc >> 1)];
    int hm = l >> 6, wm = l & 63;
    bool qhle = (nc >> 1) < 2;          // quadrants 0,1: h <= hm
    bool qwle = ((nc >> 1) & 1) == 0;   // quadrants 0,2: w <= wm
#pragma unroll
    for (int t2 = 0; t2 < 4; ++t2) {
        int idx = tid + t2 * 512;
        if (idx < 1584) {
            int pr = idx / 264; int rem = idx - pr * 264;
            int pc = rem >> 2;  int part = rem & 3;
            int grow = h0 - 1 + pr, gcol = pc - 1;
            union { int4 v; unsigned short us[8]; } u; u.v = sv[t2];
            bool inb = ((unsigned)grow < 64u) && ((unsigned)gcol < 64u);
            bool hok = qhle ? (grow <= hm) : (grow >= hm);
            bool wok = qwle ? (gcol <= wm) : (gcol >= wm);
            if (inb && hok && wok) {
                union { int4 v; unsigned short us[8]; } Lu;
                Lu.v = *(const int4*)(Lval + b * 256 + nc * 32 + part * 8);
#pragma unroll
                for (int k = 0; k < 8; ++k)
                    if (Lu.us[k] > u.us[k]) u.us[k] = Lu.us[k];  // bf16 >=0: bit-compare valid
            }
            *(int4*)(&Bw[(pr * 66 + pc) * 40 + part * 8]) = u.v;
        }
    }
}

// ---------------------------------------------------------------------------
// Conv v7: R8's 3-tap phases + global_load_lds A staging, PLUS m-granular
// operand pipeline at NET-ZERO register cost.
//   R9 lesson: acc(128 AGPR)+VGPR(128) = the full 256 budget at 2 waves/SIMD;
//   any extra named state spills (R9: +48 VGPR -> WRITE_SIZE +9.7MB scratch,
//   107us). v7 keeps the operand live-set at 64 VGPR (4 B-frags + 2x2 A
//   ping-pong) and frees sv[4] (16 VGPR) by moving load_B from sub0 to sub2.
//   Per m-step: prefetch a[m+1] (2 ds_read_b128, ~24cy) under 4 MFMAs
//   (~32cy/CU) -> LDS reads overlap MFMA instead of serializing.
//   Spill check: WRITE_SIZE must stay 65536 KB.
// LDS: As 2x48KB + Bs 2x31.7KB = 161.7 KB, 1 block/CU. Grid 256.
// ---------------------------------------------------------------------------
__global__ __launch_bounds__(512, 2) void conv_mfma(const unsigned short* __restrict__ xsqN,
                                                    const unsigned short* __restrict__ wa,
                                                    const float* __restrict__ bias,
                                                    const int* __restrict__ lm,
                                                    const unsigned short* __restrict__ Lval,
                                                    float* __restrict__ out) {
    int pt = blockIdx.x;              // b*16 + hq
    int b  = pt >> 4;
    int h0 = (pt & 15) * 4;
    int tid  = threadIdx.x;
    int lane = tid & 63;
    int wv   = tid >> 6;
    int wy = wv >> 2, wx = wv & 3;    // co half / image row
    int l31 = lane & 31, qh = lane >> 5;

    __shared__ unsigned short Bs[2][6 * 66 * 40];   // 63.4 KB
    __shared__ unsigned short As[2][3 * 8192];      // 98.3 KB (3 taps/phase)

    f32x16 acc[4][2];
#pragma unroll
    for (int mt = 0; mt < 4; ++mt)
#pragma unroll
        for (int nt = 0; nt < 2; ++nt)
#pragma unroll
            for (int r = 0; r < 16; ++r) acc[mt][nt][r] = 0.f;

    // ---- prologue: B(cib=0) into Bs[0]; A phase 0 (chunks 0..2) into As[0]
    {
        int4 sv[4];
        load_B(sv, xsqN, b, h0, 0, tid);
        const unsigned short* s0 = wa + wv * 3072 + lane * 8;
#pragma unroll
        for (int k = 0; k < 6; ++k)
            __builtin_amdgcn_global_load_lds(s0 + k * 512, &As[0][wv * 3072 + k * 512], 16, 0, 0);
        store_B(sv, &Bs[0][0], Lval, lm, b, h0, 0, tid);
    }
    __syncthreads();

    for (int cib = 0; cib < 8; ++cib) {
#pragma unroll
        for (int sub = 0; sub < 3; ++sub) {
            int ph = cib * 3 + sub;

            // ---- A DMA stage for next phase (issued first: max MFMA cover)
            if (ph < 23) {
                const unsigned short* s0 = wa + (size_t)(ph + 1) * 24576 + wv * 3072 + lane * 8;
                unsigned short* d0 = &As[(ph + 1) & 1][wv * 3072];
#pragma unroll
                for (int k = 0; k < 6; ++k)
                    __builtin_amdgcn_global_load_lds(s0 + k * 512, d0 + k * 512, 16, 0, 0);
            }

            // ---- MFMA: 3 taps, B-frags per tap + m-granular A ping-pong ----
            const unsigned short* Ab = &As[ph & 1][0];
            const unsigned short* Bb = &Bs[cib & 1][0];

            bf16x8 bf[2][2];    // [n][s] current tap's B fragments
            bf16x8 aa[2][2];    // [buf][s] A ping-pong — all indices compile-time

            // preload aa[0] = (tt=0, m=0)
            {
                const bf16x8* ap = (const bf16x8*)(Ab + (((wy * 4 + 0) * 64 + lane) << 3));
                aa[0][0] = ap[0];
                aa[0][1] = ap[512];
            }

#pragma unroll
            for (int tt = 0; tt < 3; ++tt) {
                int j  = sub * 3 + tt;            // compile-time after unroll
                int r  = wx + j / 3;
                int w0 = l31 + j % 3;
                const unsigned short* Bp = Bb + (r * 66 + w0) * 40 + qh * 8;
                // B frags for this tap (WAR on prior tap's last MFMAs keeps order)
                bf[0][0] = *(const bf16x8*)(Bp);
                bf[0][1] = *(const bf16x8*)(Bp + 16);
                bf[1][0] = *(const bf16x8*)(Bp + 1280);
                bf[1][1] = *(const bf16x8*)(Bp + 1296);
#pragma unroll
                for (int m = 0; m < 4; ++m) {
                    const int p = m & 1;
                    // prefetch next A pair into the other buffer
                    if (m < 3) {
                        const bf16x8* ap = (const bf16x8*)(Ab + tt * 8192 + (((wy * 4 + m + 1) * 64 + lane) << 3));
                        aa[p ^ 1][0] = ap[0];
                        aa[p ^ 1][1] = ap[512];
                    } else if (tt < 2) {
                        const bf16x8* ap = (const bf16x8*)(Ab + (tt + 1) * 8192 + (((wy * 4 + 0) * 64 + lane) << 3));
                        aa[p ^ 1][0] = ap[0];
                        aa[p ^ 1][1] = ap[512];
                    }
                    // 4 MFMAs for this m (K=32 via s=0,1)
                    acc[m][0] = __builtin_amdgcn_mfma_f32_32x32x16_bf16(aa[p][0], bf[0][0], acc[m][0], 0, 0, 0);
                    acc[m][1] = __builtin_amdgcn_mfma_f32_32x32x16_bf16(aa[p][0], bf[1][0], acc[m][1], 0, 0, 0);
                    acc[m][0] = __builtin_amdgcn_mfma_f32_32x32x16_bf16(aa[p][1], bf[0][1], acc[m][0], 0, 0, 0);
                    acc[m][1] = __builtin_amdgcn_mfma_f32_32x32x16_bf16(aa[p][1], bf[1][1], acc[m][1], 0, 0, 0);
                }
            }

            // ---- B load + rect-max store for cib+1 (sv scoped HERE: frees
            //      16 VGPR during the MFMA sections; exposed L2 latency only)
            if (sub == 2 && cib < 7) {
                int4 sv[4];
                load_B(sv, xsqN, b, h0, cib + 1, tid);
                store_B(sv, &Bs[(cib + 1) & 1][0], Lval, lm, b, h0, cib + 1, tid);
            }

            __syncthreads();
        }
    }

    // ---- epilogue ----
    int h = h0 + wx;
#pragma unroll
    for (int mt = 0; mt < 4; ++mt) {
#pragma unroll
        for (int nt = 0; nt < 2; ++nt) {
#pragma unroll
            for (int r = 0; r < 16; ++r) {
                int row = (r & 3) + 8 * (r >> 2) + 4 * qh;
                int co  = wy * 128 + mt * 32 + row;
                int w   = nt * 32 + l31;
                out[(((size_t)(b * 256 + co)) * 64 + h) * 64 + w] = acc[mt][nt][r] + bias[co];
            }
        }
    }
}

// ---------------------------------------------------------------------------
extern "C" void kernel_launch(void* const* d_in, const int* in_sizes, int n_in,
                              void* d_out, int out_size, void* d_ws, size_t ws_size,
                              hipStream_t stream) {
    const float* x      = (const float*)d_in[0];
    const float* weight = (const float*)d_in[1];
    const float* bias   = (const float*)d_in[2];
    float* out = (float*)d_out;

    char* ws = (char*)d_ws;
    int*            lmp  = (int*)ws;                         // 64 ints @0
    float*          pval = (float*)(ws + 256);               // 4096 f
    int*            pidx = (int*)(ws + 256 + 16384);         // 4096 i
    unsigned short* Lval = (unsigned short*)(ws + 256 + 32768);  // 4096 ush
    unsigned short* Wa   = (unsigned short*)(ws + 49152);    // 1.18 MB
    unsigned short* xsqN = (unsigned short*)(ws + 49152 + 1179648); // NHWC bf16 33.55 MB

    hipLaunchKernelGGL(fused_energy, dim3(1024), dim3(256), 0, stream, x, xsqN, pval, pidx);
    hipLaunchKernelGGL(energy_final, dim3(64), dim3(64), 0, stream, pval, pidx, lmp, xsqN, Lval);
    hipLaunchKernelGGL(wt_pack, dim3(64), dim3(256), 0, stream, weight, Wa);
    hipLaunchKernelGGL(conv_mfma, dim3(256), dim3(512), 0, stream, xsqN, Wa, bias, lmp, Lval, out);
}

// Round 12
// 182.081 us; speedup vs baseline: 1.0804x; 1.0283x over previous
//
#include <hip/hip_runtime.h>
#include <cstddef>

#define B_   16
#define C_   256
#define HW_  4096

typedef __attribute__((ext_vector_type(8)))  short bf16x8;
typedef __attribute__((ext_vector_type(16))) float f32x16;

static __device__ __forceinline__ unsigned short f2bf(float f) {
    unsigned int u = __float_as_uint(f);
    u += 0x7fffu + ((u >> 16) & 1u);          // RNE
    return (unsigned short)(u >> 16);
}

// ---------------------------------------------------------------------------
// Kernel 1: fused_energy (blocks 0..1023) MERGED with wt_pack (blocks
// 1024..1087) — the two are mutually independent; merging kills one launch.
// LDS is a union so the fused_energy path keeps its 37KB footprint.
// ---------------------------------------------------------------------------
__global__ __launch_bounds__(256) void fe_wp(const float* __restrict__ x,
                                             unsigned short* __restrict__ xsqN,
                                             float* __restrict__ pval,
                                             int* __restrict__ pidx,
                                             const float* __restrict__ w,
                                             unsigned short* __restrict__ wa) {
    __shared__ union {
        struct { float earr[4][4][64]; unsigned short tile[64][264]; } fe;
        unsigned short wlds[32][292];
    } sm;

    int tid = threadIdx.x;

    if (blockIdx.x >= 1024) {
        // ---------------- wt_pack body (verified R8), blk 0..63 ----------------
        int blk = blockIdx.x - 1024;
        int cog = blk >> 3, cib = blk & 7;
        {
            int co_l = tid >> 3;          // 0..31
            int seg  = tid & 7;           // 0..7, 36 consecutive floats each
            const float* src = w + ((size_t)((cog * 32 + co_l) * 256 + cib * 32)) * 9 + seg * 36;
#pragma unroll
            for (int f4 = 0; f4 < 9; ++f4) {
                float4 v = *(const float4*)(src + f4 * 4);
                uint2 p;
                p.x = (unsigned)f2bf(v.x) | ((unsigned)f2bf(v.y) << 16);
                p.y = (unsigned)f2bf(v.z) | ((unsigned)f2bf(v.w) << 16);
                *(uint2*)(&sm.wlds[co_l][seg * 36 + f4 * 4]) = p;
            }
        }
        __syncthreads();
        for (int idx = tid; idx < 1152; idx += 256) {   // 9j x 2s x 64 lanes
            int lane = idx & 63;
            int s    = (idx >> 6) & 1;
            int j    = idx >> 7;          // 0..8
            int co_l = lane & 31;
            int k0   = s * 16 + (lane >> 5) * 8;
            union { unsigned short us[8]; int4 v; } u;
#pragma unroll
            for (int jj = 0; jj < 8; ++jj)
                u.us[jj] = sm.wlds[co_l][(k0 + jj) * 9 + j];
            int ob = (cib * 9 + j) * 16 + s * 8 + cog;   // cib-major chunk order
            *(int4*)(wa + ((size_t)ob * 64 + lane) * 8) = u.v;
        }
        return;
    }

    // ---------------- fused_energy body (verified R5) ----------------
    int blk = blockIdx.x;
    int b = blk >> 6, h = blk & 63;
    int tl  = tid >> 4;           // 0..15 channel-lane group
    int w4  = (tid & 15) << 2;    // w base 0,4,...,60
    int wv  = tid >> 6;           // wave 0..3
    const float* xb = x + (size_t)b * C_ * HW_ + h * 64 + w4;

    float e[4][4];                // [quadrant][ww]
#pragma unroll
    for (int q = 0; q < 4; ++q)
#pragma unroll
        for (int ww = 0; ww < 4; ++ww) e[q][ww] = 0.f;

#pragma unroll
    for (int i = 0; i < 4; ++i) {             // quadrant = i (compile-time)
        int c4 = tl * 4 + 64 * i;             // 4 consecutive channels
        float sq[4][4];                       // [k=channel][ww]
#pragma unroll
        for (int k = 0; k < 4; ++k) {
            float4 v = *(const float4*)(xb + (size_t)(c4 + k) * HW_);
            sq[k][0] = v.x * v.x; sq[k][1] = v.y * v.y;
            sq[k][2] = v.z * v.z; sq[k][3] = v.w * v.w;
            e[i][0] += sq[k][0]; e[i][1] += sq[k][1];
            e[i][2] += sq[k][2]; e[i][3] += sq[k][3];
        }
#pragma unroll
        for (int ww = 0; ww < 4; ++ww) {      // pack 4 channels -> ushort4
            uint2 p;
            p.x = (unsigned)f2bf(sq[0][ww]) | ((unsigned)f2bf(sq[1][ww]) << 16);
            p.y = (unsigned)f2bf(sq[2][ww]) | ((unsigned)f2bf(sq[3][ww]) << 16);
            *(uint2*)(&sm.fe.tile[w4 + ww][c4]) = p;
        }
    }

    // wave-local reduce over the 4 tl-groups within this wave (tid bits 4,5)
#pragma unroll
    for (int q = 0; q < 4; ++q)
#pragma unroll
        for (int ww = 0; ww < 4; ++ww) {
            float v = e[q][ww];
            v += __shfl_xor(v, 16);
            v += __shfl_xor(v, 32);
            e[q][ww] = v;
        }
    if ((tid & 48) == 0) {
#pragma unroll
        for (int q = 0; q < 4; ++q) {
            float4 v; v.x = e[q][0]; v.y = e[q][1]; v.z = e[q][2]; v.w = e[q][3];
            *(float4*)&sm.fe.earr[wv][q][w4] = v;
        }
    }
    __syncthreads();

    // contiguous NHWC stores: 32 lanes cover one 512B row segment
    size_t base = (size_t)(b * 64 + h) * 64 * 256;
#pragma unroll
    for (int it = 0; it < 8; ++it) {
        int row  = it * 8 + (tid >> 5);
        int col8 = (tid & 31) * 8;
        *(int4*)(xsqN + base + (size_t)row * 256 + col8) = *(int4*)&sm.fe.tile[row][col8];
    }

    int q = tid >> 6;
    int ww = tid & 63;
    float ev = sm.fe.earr[0][q][ww] + sm.fe.earr[1][q][ww] + sm.fe.earr[2][q][ww] + sm.fe.earr[3][q][ww];
    int ix = h * 64 + ww;
#pragma unroll
    for (int off = 32; off; off >>= 1) {
        float ov = __shfl_down(ev, off);
        int   oi = __shfl_down(ix, off);
        if (ov > ev || (ov == ev && oi < ix)) { ev = ov; ix = oi; }
    }
    if ((tid & 63) == 0) {
        pval[(b * 64 + h) * 4 + q] = ev;
        pidx[(b * 64 + h) * 4 + q] = ix;
    }
}

// ---------------------------------------------------------------------------
// B-tile helpers (512-thread block): register load, then rect-max + LDS store.
// Landmark data now comes from block-local LDS (lmq/Lv) — computed inline in
// the conv prologue, eliminating the energy_final launch.
// ---------------------------------------------------------------------------
static __device__ __forceinline__ void load_B(int4 sv[4],
                                              const unsigned short* __restrict__ xsqN,
                                              int b, int h0, int nc, int tid) {
#pragma unroll
    for (int t2 = 0; t2 < 4; ++t2) {
        int idx = tid + t2 * 512;
        int4 v = {0, 0, 0, 0};
        if (idx < 1584) {
            int pr = idx / 264; int rem = idx - pr * 264;
            int pc = rem >> 2;  int part = rem & 3;
            int grow = h0 - 1 + pr, gcol = pc - 1;
            if ((unsigned)grow < 64u && (unsigned)gcol < 64u)
                v = *(const int4*)(xsqN + (((size_t)(b * 64 + grow) * 64 + gcol) * 256 + nc * 32 + part * 8));
        }
        sv[t2] = v;
    }
}

static __device__ __forceinline__ void store_B(const int4 sv[4],
                                               unsigned short* __restrict__ Bw,
                                               const unsigned short* __restrict__ Lv,
                                               const int* __restrict__ lmq,
                                               int h0, int nc, int tid) {
    int l = lmq[nc >> 1];
    int hm = l >> 6, wm = l & 63;
    bool qhle = (nc >> 1) < 2;          // quadrants 0,1: h <= hm
    bool qwle = ((nc >> 1) & 1) == 0;   // quadrants 0,2: w <= wm
#pragma unroll
    for (int t2 = 0; t2 < 4; ++t2) {
        int idx = tid + t2 * 512;
        if (idx < 1584) {
            int pr = idx / 264; int rem = idx - pr * 264;
            int pc = rem >> 2;  int part = rem & 3;
            int grow = h0 - 1 + pr, gcol = pc - 1;
            union { int4 v; unsigned short us[8]; } u; u.v = sv[t2];
            bool inb = ((unsigned)grow < 64u) && ((unsigned)gcol < 64u);
            bool hok = qhle ? (grow <= hm) : (grow >= hm);
            bool wok = qwle ? (gcol <= wm) : (gcol >= wm);
            if (inb && hok && wok) {
                union { int4 v; unsigned short us[8]; } Lu;
                Lu.v = *(const int4*)(Lv + nc * 32 + part * 8);
#pragma unroll
                for (int k = 0; k < 8; ++k)
                    if (Lu.us[k] > u.us[k]) u.us[k] = Lu.us[k];  // bf16 >=0: bit-compare valid
            }
            *(int4*)(&Bw[(pr * 66 + pc) * 40 + part * 8]) = u.v;
        }
    }
}

// ---------------------------------------------------------------------------
// Conv v8 = v7 (verified R11) + INLINE landmark finalize (replaces the
// energy_final kernel): each block re-derives lm[b][q] from pval/pidx (4x
// 64-wide shuffle reductions, ~1KB read) and gathers the 512B landmark row
// from xsqN into LDS. Redundant across the 16 blocks sharing b — trivially
// cheap vs. a dedicated launch.
// LDS: As 2x48KB + Bs 2x31.7KB + Lv 512B + lmq = 162.2 KB, 1 block/CU.
// ---------------------------------------------------------------------------
__global__ __launch_bounds__(512, 2) void conv_mfma(const unsigned short* __restrict__ xsqN,
                                                    const unsigned short* __restrict__ wa,
                                                    const float* __restrict__ bias,
                                                    const float* __restrict__ pval,
                                                    const int* __restrict__ pidx,
                                                    float* __restrict__ out) {
    int pt = blockIdx.x;              // b*16 + hq
    int b  = pt >> 4;
    int h0 = (pt & 15) * 4;
    int tid  = threadIdx.x;
    int lane = tid & 63;
    int wv   = tid >> 6;
    int wy = wv >> 2, wx = wv & 3;    // co half / image row
    int l31 = lane & 31, qh = lane >> 5;

    __shared__ unsigned short Bs[2][6 * 66 * 40];   // 63.4 KB
    __shared__ unsigned short As[2][3 * 8192];      // 98.3 KB (3 taps/phase)
    __shared__ __align__(16) unsigned short Lv[256];
    __shared__ int lmq[4];

    f32x16 acc[4][2];
#pragma unroll
    for (int mt = 0; mt < 4; ++mt)
#pragma unroll
        for (int nt = 0; nt < 2; ++nt)
#pragma unroll
            for (int r = 0; r < 16; ++r) acc[mt][nt][r] = 0.f;

    // ---- prologue ----
    {
        // A phase 0 DMA first (latency hides under landmark work)
        const unsigned short* s0 = wa + wv * 3072 + lane * 8;
#pragma unroll
        for (int k = 0; k < 6; ++k)
            __builtin_amdgcn_global_load_lds(s0 + k * 512, &As[0][wv * 3072 + k * 512], 16, 0, 0);

        int4 sv[4];
        load_B(sv, xsqN, b, h0, 0, tid);

        // inline energy_final: wave q<4 reduces over h for quadrant q
        if (wv < 4) {
            int q = wv;
            float ev = pval[(b * 64 + lane) * 4 + q];
            int   ix = pidx[(b * 64 + lane) * 4 + q];
#pragma unroll
            for (int off = 32; off; off >>= 1) {
                float ov = __shfl_down(ev, off);
                int   oi = __shfl_down(ix, off);
                if (ov > ev || (ov == ev && oi < ix)) { ev = ov; ix = oi; }
            }
            if (lane == 0) lmq[q] = ix;
        }
        __syncthreads();
        // landmark value row gather (512B)
        if (tid < 256) {
            int c = tid, q = c >> 6;
            int l = lmq[q];
            Lv[c] = xsqN[((size_t)((b * 64 + (l >> 6)) * 64 + (l & 63))) * 256 + c];
        }
        __syncthreads();

        store_B(sv, &Bs[0][0], Lv, lmq, h0, 0, tid);
    }
    __syncthreads();

    for (int cib = 0; cib < 8; ++cib) {
#pragma unroll
        for (int sub = 0; sub < 3; ++sub) {
            int ph = cib * 3 + sub;

            // ---- A DMA stage for next phase (issued first: max MFMA cover)
            if (ph < 23) {
                const unsigned short* s0 = wa + (size_t)(ph + 1) * 24576 + wv * 3072 + lane * 8;
                unsigned short* d0 = &As[(ph + 1) & 1][wv * 3072];
#pragma unroll
                for (int k = 0; k < 6; ++k)
                    __builtin_amdgcn_global_load_lds(s0 + k * 512, d0 + k * 512, 16, 0, 0);
            }

            // ---- MFMA: 3 taps, B-frags per tap + m-granular A ping-pong ----
            const unsigned short* Ab = &As[ph & 1][0];
            const unsigned short* Bb = &Bs[cib & 1][0];

            bf16x8 bf[2][2];    // [n][s] current tap's B fragments
            bf16x8 aa[2][2];    // [buf][s] A ping-pong — all indices compile-time

            // preload aa[0] = (tt=0, m=0)
            {
                const bf16x8* ap = (const bf16x8*)(Ab + (((wy * 4 + 0) * 64 + lane) << 3));
                aa[0][0] = ap[0];
                aa[0][1] = ap[512];
            }

#pragma unroll
            for (int tt = 0; tt < 3; ++tt) {
                int j  = sub * 3 + tt;            // compile-time after unroll
                int r  = wx + j / 3;
                int w0 = l31 + j % 3;
                const unsigned short* Bp = Bb + (r * 66 + w0) * 40 + qh * 8;
                // B frags for this tap (WAR on prior tap's last MFMAs keeps order)
                bf[0][0] = *(const bf16x8*)(Bp);
                bf[0][1] = *(const bf16x8*)(Bp + 16);
                bf[1][0] = *(const bf16x8*)(Bp + 1280);
                bf[1][1] = *(const bf16x8*)(Bp + 1296);
#pragma unroll
                for (int m = 0; m < 4; ++m) {
                    const int p = m & 1;
                    // prefetch next A pair into the other buffer
                    if (m < 3) {
                        const bf16x8* ap = (const bf16x8*)(Ab + tt * 8192 + (((wy * 4 + m + 1) * 64 + lane) << 3));
                        aa[p ^ 1][0] = ap[0];
                        aa[p ^ 1][1] = ap[512];
                    } else if (tt < 2) {
                        const bf16x8* ap = (const bf16x8*)(Ab + (tt + 1) * 8192 + (((wy * 4 + 0) * 64 + lane) << 3));
                        aa[p ^ 1][0] = ap[0];
                        aa[p ^ 1][1] = ap[512];
                    }
                    // 4 MFMAs for this m (K=32 via s=0,1)
                    acc[m][0] = __builtin_amdgcn_mfma_f32_32x32x16_bf16(aa[p][0], bf[0][0], acc[m][0], 0, 0, 0);
                    acc[m][1] = __builtin_amdgcn_mfma_f32_32x32x16_bf16(aa[p][0], bf[1][0], acc[m][1], 0, 0, 0);
                    acc[m][0] = __builtin_amdgcn_mfma_f32_32x32x16_bf16(aa[p][1], bf[0][1], acc[m][0], 0, 0, 0);
                    acc[m][1] = __builtin_amdgcn_mfma_f32_32x32x16_bf16(aa[p][1], bf[1][1], acc[m][1], 0, 0, 0);
                }
            }

            // ---- B load + rect-max store for cib+1 (sv scoped here)
            if (sub == 2 && cib < 7) {
                int4 sv[4];
                load_B(sv, xsqN, b, h0, cib + 1, tid);
                store_B(sv, &Bs[(cib + 1) & 1][0], Lv, lmq, h0, cib + 1, tid);
            }

            __syncthreads();
        }
    }

    // ---- epilogue ----
    int h = h0 + wx;
#pragma unroll
    for (int mt = 0; mt < 4; ++mt) {
#pragma unroll
        for (int nt = 0; nt < 2; ++nt) {
#pragma unroll
            for (int r = 0; r < 16; ++r) {
                int row = (r & 3) + 8 * (r >> 2) + 4 * qh;
                int co  = wy * 128 + mt * 32 + row;
                int w   = nt * 32 + l31;
                out[(((size_t)(b * 256 + co)) * 64 + h) * 64 + w] = acc[mt][nt][r] + bias[co];
            }
        }
    }
}

// ---------------------------------------------------------------------------
extern "C" void kernel_launch(void* const* d_in, const int* in_sizes, int n_in,
                              void* d_out, int out_size, void* d_ws, size_t ws_size,
                              hipStream_t stream) {
    const float* x      = (const float*)d_in[0];
    const float* weight = (const float*)d_in[1];
    const float* bias   = (const float*)d_in[2];
    float* out = (float*)d_out;

    char* ws = (char*)d_ws;
    float*          pval = (float*)(ws + 256);               // 4096 f
    int*            pidx = (int*)(ws + 256 + 16384);         // 4096 i
    unsigned short* Wa   = (unsigned short*)(ws + 49152);    // 1.18 MB
    unsigned short* xsqN = (unsigned short*)(ws + 49152 + 1179648); // NHWC bf16 33.55 MB

    // 2 launches: [fused_energy || wt_pack], then [conv + inline finalize]
    hipLaunchKernelGGL(fe_wp, dim3(1088), dim3(256), 0, stream, x, xsqN, pval, pidx, weight, Wa);
    hipLaunchKernelGGL(conv_mfma, dim3(256), dim3(512), 0, stream, xsqN, Wa, bias, pval, pidx, out);
}